// Round 1
// baseline (65566.809 us; speedup 1.0000x reference)
//
#include <hip/hip_runtime.h>
#include <math.h>

// Model: 10 parallel LSTMs -> MI-LSTM w/ stream attention -> linear head.
// All f32 (no fp32-input MFMA on CDNA4; accuracy threshold requires f32).
// Workspace requirement: ~519 MiB.
//
// Layout (floats):
#define SS 10
#define TT 256
#define BB 128
#define HH 128
#define II 128
#define G4 512     // 4H
#define ZK 256     // I + H (fused [x|h] contraction)
#define NCOL 2944  // phase-D fused weight columns: Ui(1280)|Uc(1280)|Uf(128)|Uo(128)|Wa(128)

#define SZ_W2T   (SS*ZK*G4)        // 1,310,720
#define SZ_BIAS2 (SS*G4)           // 5,120
#define SZ_UBIG  (HH*NCOL)         // 376,832
#define SZ_TILDE (SS*TT*BB*HH)     // 41,943,040
#define SZ_X     (TT*SS*BB*HH)     // 41,943,040
#define SZ_XFO   (TT*BB*HH)        // 4,194,304

#define OFF_W2T   0
#define OFF_BIAS2 (OFF_W2T + SZ_W2T)
#define OFF_UBIG  (OFF_BIAS2 + SZ_BIAS2)
#define OFF_TILDE (OFF_UBIG + SZ_UBIG)
#define OFF_XI    (OFF_TILDE + SZ_TILDE)
#define OFF_XC    (OFF_XI + SZ_X)
#define OFF_XF    (OFF_XC + SZ_X)
#define OFF_XO    (OFF_XF + SZ_XFO)

__device__ __forceinline__ float sigf(float x){ return 1.0f/(1.0f+expf(-x)); }

// ---------------- prep: fused transposed LSTM weights + bias ----------------
// w2t[s][kk][j]: kk<128 -> Wih[s][j][kk]; else Whh[s][j][kk-128]. bias2 = bih+bhh.
__global__ __launch_bounds__(256) void prep_w2t(const float* __restrict__ Wih, const float* __restrict__ Whh,
                                                const float* __restrict__ bih, const float* __restrict__ bhh,
                                                float* __restrict__ w2t, float* __restrict__ bias2){
  int idx = blockIdx.x*256 + threadIdx.x;
  if (idx < SZ_W2T){
    int j = idx % G4; int kk = (idx / G4) % ZK; int s = idx / (G4*ZK);
    float v = (kk < II) ? Wih[(s*G4 + j)*II + kk] : Whh[(s*G4 + j)*HH + (kk - II)];
    w2t[idx] = v;
  }
  if (idx < SZ_BIAS2) bias2[idx] = bih[idx] + bhh[idx];
}

// ubig[h][col]: col<1280 Ui[k][h][d]; <2560 Uc; <2688 Uf[h][d]; <2816 Uo; else Wa.
__global__ __launch_bounds__(256) void prep_ubig(const float* __restrict__ Ui, const float* __restrict__ Uc,
                                                 const float* __restrict__ Uf, const float* __restrict__ Uo,
                                                 const float* __restrict__ Wa, float* __restrict__ ubig){
  int idx = blockIdx.x*256 + threadIdx.x;
  if (idx >= SZ_UBIG) return;
  int col = idx % NCOL; int h = idx / NCOL;
  float v;
  if (col < 1280){ int k = col >> 7, d = col & 127; v = Ui[(k*HH + h)*HH + d]; }
  else if (col < 2560){ int c2 = col - 1280; int k = c2 >> 7, d = c2 & 127; v = Uc[(k*HH + h)*HH + d]; }
  else if (col < 2688){ v = Uf[h*HH + (col - 2560)]; }
  else if (col < 2816){ v = Uo[h*HH + (col - 2688)]; }
  else               { v = Wa[h*HH + (col - 2816)]; }
  ubig[idx] = v;
}

// ---------------- phase B: fused 10x LSTM scan ----------------
// 160 blocks x 512 thr; block = (stream s, 8 batch rows). Rows are recurrence-
// independent -> no cross-block traffic. z=[x_t|h] in LDS; W2T streamed from L2.
// Block-id swizzle groups each stream's blocks onto few XCDs so W2T stays L2-resident.
__global__ __launch_bounds__(512) void lstm_scan(const float* __restrict__ feat, const float* __restrict__ w2t,
                                                 const float* __restrict__ bias2, float* __restrict__ tilde){
  // swizzle: physical p -> logical g so XCD x (p%8) serves contiguous stream chunk
  int p = blockIdx.x;                 // 0..159
  int g = (p & 7) * 20 + (p >> 3);    // inverse of p = g/20 + 8*(g%20)
  int s = g >> 4; int rb = g & 15; int b0 = rb * 8;
  int tid = threadIdx.x;
  __shared__ float z[8][ZK];          // [row][x(128)|h(128)]
  __shared__ float gl[8][G4];         // activated gates
  const float* w2ts = w2t + s*ZK*G4;
  float bj = bias2[s*G4 + tid];
  float c0 = 0.f, c1 = 0.f;
  {
    int q = tid*2; int r = q >> 7; int k = q & 127;
    z[r][128+k] = 0.f; z[r][128+k+1] = 0.f;
    const float* xrow = feat + ((s*TT + 0)*BB + (b0+r))*II;
    float2 xv = *(const float2*)(xrow + k);
    z[r][k] = xv.x; z[r][k+1] = xv.y;
  }
  __syncthreads();
  for (int t = 0; t < TT; ++t){
    float acc[8];
    #pragma unroll
    for (int r=0;r<8;++r) acc[r] = bj;
    for (int kk = 0; kk < ZK; kk += 4){
      const float* wp = w2ts + kk*G4 + tid;
      float w0 = wp[0], w1 = wp[G4], w2 = wp[2*G4], w3 = wp[3*G4];
      #pragma unroll
      for (int r=0;r<8;++r){
        float4 zv = *(const float4*)&z[r][kk];
        acc[r] = fmaf(zv.w, w3, fmaf(zv.z, w2, fmaf(zv.y, w1, fmaf(zv.x, w0, acc[r]))));
      }
    }
    int gtype = tid >> 7;    // 0:i 1:f 2:g 3:o
    #pragma unroll
    for (int r=0;r<8;++r){
      float v = acc[r];
      v = (gtype == 2) ? tanhf(v) : sigf(v);
      gl[r][tid] = v;
    }
    __syncthreads();
    {
      int q = tid*2; int r = q >> 7; int k = q & 127;
      float si0 = gl[r][k],     si1 = gl[r][k+1];
      float sf0 = gl[r][128+k], sf1 = gl[r][128+k+1];
      float tg0 = gl[r][256+k], tg1 = gl[r][256+k+1];
      float so0 = gl[r][384+k], so1 = gl[r][384+k+1];
      c0 = sf0*c0 + si0*tg0;
      c1 = sf1*c1 + si1*tg1;
      float h0 = so0*tanhf(c0), h1 = so1*tanhf(c1);
      z[r][128+k] = h0; z[r][128+k+1] = h1;
      float2 tv = make_float2(fmaxf(h0,0.f), fmaxf(h1,0.f));
      *(float2*)&tilde[((s*TT + t)*BB + (b0+r))*HH + k] = tv;
      if (t+1 < TT){
        const float* xrow = feat + ((s*TT + (t+1))*BB + (b0+r))*II;
        float2 xv = *(const float2*)(xrow + k);
        z[r][k] = xv.x; z[r][k+1] = xv.y;
      }
    }
    __syncthreads();
  }
}

// ---------------- phase C: xi/xc projections ----------------
// grid (256 m-tiles, 10 k, 2 {Wi,Wc}); W in LDS (64KB), A rows read once.
__global__ __launch_bounds__(256) void proj_ic(const float* __restrict__ tilde,
                                               const float* __restrict__ Wi, const float* __restrict__ bi,
                                               const float* __restrict__ Wc, const float* __restrict__ bc,
                                               float* __restrict__ xi, float* __restrict__ xc){
  const int k = blockIdx.y;
  const int isc = blockIdx.z;
  const float* W = (isc ? Wc : Wi) + k*HH*HH;
  const float* bias = (isc ? bc : bi) + k*HH;
  float* out = isc ? xc : xi;
  const int m0 = blockIdx.x * 128;
  const int tid = threadIdx.x;
  __shared__ float Wl[HH*HH];
  __shared__ float Al[32*HH];
  for (int u = 0; u < 64; ++u) Wl[u*256 + tid] = W[u*256 + tid];
  const int tx = tid & 31, ty = tid >> 5;
  const int d0 = tx*4;
  float4 bv = *(const float4*)&bias[d0];
  __syncthreads();
  for (int ch = 0; ch < 4; ++ch){
    const float* Arow = tilde + (size_t)(k*TT*BB + m0 + ch*32)*HH;
    #pragma unroll
    for (int u = 0; u < 4; ++u)
      *(float4*)&Al[u*1024 + tid*4] = *(const float4*)&Arow[u*1024 + tid*4];
    __syncthreads();
    float4 a0 = bv, a1 = bv, a2 = bv, a3 = bv;
    for (int h = 0; h < HH; ++h){
      float4 w4 = *(const float4*)&Wl[h*HH + d0];
      float A0 = Al[(ty   )*HH + h], A1 = Al[(ty+ 8)*HH + h];
      float A2 = Al[(ty+16)*HH + h], A3 = Al[(ty+24)*HH + h];
      a0.x = fmaf(A0,w4.x,a0.x); a0.y = fmaf(A0,w4.y,a0.y); a0.z = fmaf(A0,w4.z,a0.z); a0.w = fmaf(A0,w4.w,a0.w);
      a1.x = fmaf(A1,w4.x,a1.x); a1.y = fmaf(A1,w4.y,a1.y); a1.z = fmaf(A1,w4.z,a1.z); a1.w = fmaf(A1,w4.w,a1.w);
      a2.x = fmaf(A2,w4.x,a2.x); a2.y = fmaf(A2,w4.y,a2.y); a2.z = fmaf(A2,w4.z,a2.z); a2.w = fmaf(A2,w4.w,a2.w);
      a3.x = fmaf(A3,w4.x,a3.x); a3.y = fmaf(A3,w4.y,a3.y); a3.z = fmaf(A3,w4.z,a3.z); a3.w = fmaf(A3,w4.w,a3.w);
    }
    float4 accs[4] = {a0,a1,a2,a3};
    #pragma unroll
    for (int i = 0; i < 4; ++i){
      int m = m0 + ch*32 + ty + 8*i;
      int t = m >> 7, b = m & 127;
      *(float4*)&out[((t*SS + k)*BB + b)*HH + d0] = accs[i];
    }
    __syncthreads();
  }
}

// xf/xo from mainstream tilde[0]
__global__ __launch_bounds__(256) void proj_fo(const float* __restrict__ tilde,
                                               const float* __restrict__ Wf, const float* __restrict__ bf,
                                               const float* __restrict__ Wo, const float* __restrict__ bo,
                                               float* __restrict__ xf, float* __restrict__ xo){
  const int iso = blockIdx.y;
  const float* W = iso ? Wo : Wf;
  const float* bias = iso ? bo : bf;
  float* out = iso ? xo : xf;
  const int m0 = blockIdx.x * 128;
  const int tid = threadIdx.x;
  __shared__ float Wl[HH*HH];
  __shared__ float Al[32*HH];
  for (int u = 0; u < 64; ++u) Wl[u*256 + tid] = W[u*256 + tid];
  const int tx = tid & 31, ty = tid >> 5;
  const int d0 = tx*4;
  float4 bv = *(const float4*)&bias[d0];
  __syncthreads();
  for (int ch = 0; ch < 4; ++ch){
    const float* Arow = tilde + (size_t)(m0 + ch*32)*HH;
    #pragma unroll
    for (int u = 0; u < 4; ++u)
      *(float4*)&Al[u*1024 + tid*4] = *(const float4*)&Arow[u*1024 + tid*4];
    __syncthreads();
    float4 a0 = bv, a1 = bv, a2 = bv, a3 = bv;
    for (int h = 0; h < HH; ++h){
      float4 w4 = *(const float4*)&Wl[h*HH + d0];
      float A0 = Al[(ty   )*HH + h], A1 = Al[(ty+ 8)*HH + h];
      float A2 = Al[(ty+16)*HH + h], A3 = Al[(ty+24)*HH + h];
      a0.x = fmaf(A0,w4.x,a0.x); a0.y = fmaf(A0,w4.y,a0.y); a0.z = fmaf(A0,w4.z,a0.z); a0.w = fmaf(A0,w4.w,a0.w);
      a1.x = fmaf(A1,w4.x,a1.x); a1.y = fmaf(A1,w4.y,a1.y); a1.z = fmaf(A1,w4.z,a1.z); a1.w = fmaf(A1,w4.w,a1.w);
      a2.x = fmaf(A2,w4.x,a2.x); a2.y = fmaf(A2,w4.y,a2.y); a2.z = fmaf(A2,w4.z,a2.z); a2.w = fmaf(A2,w4.w,a2.w);
      a3.x = fmaf(A3,w4.x,a3.x); a3.y = fmaf(A3,w4.y,a3.y); a3.z = fmaf(A3,w4.z,a3.z); a3.w = fmaf(A3,w4.w,a3.w);
    }
    float4 accs[4] = {a0,a1,a2,a3};
    #pragma unroll
    for (int i = 0; i < 4; ++i){
      int m = m0 + ch*32 + ty + 8*i;
      *(float4*)&out[(size_t)m*HH + d0] = accs[i];
    }
    __syncthreads();
  }
}

// ---------------- phase D: MI-LSTM scan + fused head ----------------
// 128 blocks (one per batch row) x 512 thr. Per step: 2944 length-128 dots
// against LDS-resident h (or c for the Wa block), streamed Ubig (1.5MB, L2-resident).
__global__ __launch_bounds__(512) void mi_scan(const float* __restrict__ ubig,
                                               const float* __restrict__ xi, const float* __restrict__ xc,
                                               const float* __restrict__ xf, const float* __restrict__ xo,
                                               const float* __restrict__ headW, const float* __restrict__ headb,
                                               float* __restrict__ out){
  const int b = blockIdx.x;
  const int tid = threadIdx.x;
  __shared__ __align__(16) float hL[HH];
  __shared__ __align__(16) float cL[HH];
  __shared__ __align__(16) float act[NCOL];
  __shared__ float lL[10][HH];
  __shared__ float uL[16];
  __shared__ float aL[16];
  __shared__ float red[HH];
  float hw = (tid < HH) ? headW[tid] : 0.f;
  float hb = headb[0];
  if (tid < HH){ hL[tid] = 0.f; cL[tid] = 0.f; }
  __syncthreads();
  const int wv = tid >> 6, lane = tid & 63;
  for (int t = 0; t < TT; ++t){
    // 2944 pre-activation dots
    #pragma unroll
    for (int ppp = 0; ppp < 6; ++ppp){
      int col = ppp*512 + tid;
      if (col < NCOL){
        float base; const float* av = hL;
        if (col < 1280){ int k = col >> 7, d = col & 127; base = xi[((t*SS + k)*BB + b)*HH + d]; }
        else if (col < 2560){ int c2 = col - 1280; int k = c2 >> 7, d = c2 & 127; base = xc[((t*SS + k)*BB + b)*HH + d]; }
        else if (col < 2688){ base = xf[(t*BB + b)*HH + (col - 2560)]; }
        else if (col < 2816){ base = xo[(t*BB + b)*HH + (col - 2688)]; }
        else { base = 0.f; av = cL; }
        float a0 = base, a1 = 0.f, a2 = 0.f, a3 = 0.f;
        const float* wp = ubig + col;
        for (int h = 0; h < HH; h += 4){
          float4 hv = *(const float4*)&av[h];
          a0 = fmaf(hv.x, wp[(h+0)*NCOL], a0);
          a1 = fmaf(hv.y, wp[(h+1)*NCOL], a1);
          a2 = fmaf(hv.z, wp[(h+2)*NCOL], a2);
          a3 = fmaf(hv.w, wp[(h+3)*NCOL], a3);
        }
        float accv = (a0 + a1) + (a2 + a3);
        float v;
        if (col < 1280) v = sigf(accv);
        else if (col < 2560) v = tanhf(accv);
        else if (col < 2816) v = sigf(accv);
        else v = accv;               // cw (c @ Wa), no activation
        act[col] = v;
      }
    }
    __syncthreads();
    // l = i*ctil; u[k] = tanh(sum_d l*cw)
    for (int k = wv; k < 10; k += 8){
      float s = 0.f;
      #pragma unroll
      for (int d = lane; d < HH; d += 64){
        float li = act[k*128 + d] * act[1280 + k*128 + d];
        lL[k][d] = li;
        s += li * act[2816 + d];
      }
      #pragma unroll
      for (int off = 32; off; off >>= 1) s += __shfl_down(s, off);
      if (lane == 0) uL[k] = tanhf(s);
    }
    __syncthreads();
    if (tid == 0){
      float m = -1e30f;
      for (int k = 0; k < 10; ++k) m = fmaxf(m, uL[k]);
      float ssum = 0.f; float e[10];
      for (int k = 0; k < 10; ++k){ e[k] = expf(uL[k] - m); ssum += e[k]; }
      float inv = 1.f/ssum;
      for (int k = 0; k < 10; ++k) aL[k] = e[k]*inv;
    }
    __syncthreads();
    if (tid < HH){
      int d = tid;
      float lm = 0.f;
      #pragma unroll
      for (int k = 0; k < 10; ++k) lm = fmaf(aL[k], lL[k][d], lm);
      float f = act[2560 + d], o = act[2688 + d];
      float cn = f*cL[d] + lm;
      float hn = o*tanhf(cn);
      cL[d] = cn; hL[d] = hn;
      red[d] = fmaxf(hn, 0.f) * hw;
    }
    __syncthreads();
    if (tid < 64){
      float s = red[tid] + red[tid + 64];
      #pragma unroll
      for (int off = 32; off; off >>= 1) s += __shfl_down(s, off);
      if (tid == 0) out[t*BB + b] = fmaxf(s + hb, 0.f);
    }
    __syncthreads();
  }
}

extern "C" void kernel_launch(void* const* d_in, const int* in_sizes, int n_in,
                              void* d_out, int out_size, void* d_ws, size_t ws_size,
                              hipStream_t stream) {
  const float* feat  = (const float*)d_in[0];
  const float* Wih   = (const float*)d_in[1];
  const float* Whh   = (const float*)d_in[2];
  const float* bih   = (const float*)d_in[3];
  const float* bhh   = (const float*)d_in[4];
  const float* miWi  = (const float*)d_in[5];
  const float* miUi  = (const float*)d_in[6];
  const float* mibi  = (const float*)d_in[7];
  const float* miWc  = (const float*)d_in[8];
  const float* miUc  = (const float*)d_in[9];
  const float* mibc  = (const float*)d_in[10];
  const float* miWf  = (const float*)d_in[11];
  const float* miUf  = (const float*)d_in[12];
  const float* mibf  = (const float*)d_in[13];
  const float* miWo  = (const float*)d_in[14];
  const float* miUo  = (const float*)d_in[15];
  const float* mibo  = (const float*)d_in[16];
  const float* miWa  = (const float*)d_in[17];
  const float* headW = (const float*)d_in[18];
  const float* headb = (const float*)d_in[19];
  float* out = (float*)d_out;

  float* ws    = (float*)d_ws;
  float* w2t   = ws + OFF_W2T;
  float* bias2 = ws + OFF_BIAS2;
  float* ubig  = ws + OFF_UBIG;
  float* tilde = ws + OFF_TILDE;
  float* xi    = ws + OFF_XI;
  float* xc    = ws + OFF_XC;
  float* xf    = ws + OFF_XF;
  float* xo    = ws + OFF_XO;

  prep_w2t<<<dim3(SZ_W2T/256), dim3(256), 0, stream>>>(Wih, Whh, bih, bhh, w2t, bias2);
  prep_ubig<<<dim3((SZ_UBIG+255)/256), dim3(256), 0, stream>>>(miUi, miUc, miUf, miUo, miWa, ubig);
  lstm_scan<<<dim3(160), dim3(512), 0, stream>>>(feat, w2t, bias2, tilde);
  proj_ic<<<dim3(256, SS, 2), dim3(256), 0, stream>>>(tilde, miWi, mibi, miWc, mibc, xi, xc);
  proj_fo<<<dim3(256, 2), dim3(256), 0, stream>>>(tilde, miWf, mibf, miWo, mibo, xf, xo);
  mi_scan<<<dim3(BB), dim3(512), 0, stream>>>(ubig, xi, xc, xf, xo, headW, headb, out);
}

// Round 2
// 10140.955 us; speedup vs baseline: 6.4655x; 6.4655x over previous
//
#include <hip/hip_runtime.h>
#include <math.h>

// Model: 10 parallel LSTMs -> MI-LSTM w/ stream attention -> linear head.
// All f32 (no fp32-input MFMA on CDNA4; accuracy threshold requires f32).
//
#define SS 10
#define TT 256
#define BB 128
#define HH 128
#define II 128
#define G4 512     // 4H
#define ZK 256     // I + H (fused [x|h] contraction)
#define NCOL 2944  // phase-D fused weight columns: Ui(1280)|Uc(1280)|Uf(128)|Uo(128)|Wa(128)
#define NBLK 92    // cooperative blocks: 92 x 32 cols = 2944

#define SZ_W2T   (SS*ZK*G4)        // 1,310,720
#define SZ_BIAS2 (SS*G4)           // 5,120
#define SZ_UBIG  (HH*NCOL)         // 376,832
#define SZ_TILDE (SS*TT*BB*HH)     // 41,943,040
#define SZ_X     (TT*SS*BB*HH)     // 41,943,040
#define SZ_XFO   (TT*BB*HH)        // 4,194,304

#define OFF_W2T   0
#define OFF_BIAS2 (OFF_W2T + SZ_W2T)
#define OFF_UBIG  (OFF_BIAS2 + SZ_BIAS2)
#define OFF_TILDE (OFF_UBIG + SZ_UBIG)
#define OFF_XI    (OFF_TILDE + SZ_TILDE)
#define OFF_XC    (OFF_XI + SZ_X)
#define OFF_XF    (OFF_XC + SZ_X)
#define OFF_XO    (OFF_XF + SZ_XFO)
#define OFF_HT    (OFF_XO + SZ_XFO)
#define OFF_CT    (OFF_HT + BB*HH)
#define OFF_ACT   (OFF_CT + BB*HH)
#define OFF_CNT   (OFF_ACT + BB*NCOL)

__device__ __forceinline__ float sigf(float x){ return 1.0f/(1.0f+expf(-x)); }

// ---------------- prep: fused transposed LSTM weights + bias ----------------
__global__ __launch_bounds__(256) void prep_w2t(const float* __restrict__ Wih, const float* __restrict__ Whh,
                                                const float* __restrict__ bih, const float* __restrict__ bhh,
                                                float* __restrict__ w2t, float* __restrict__ bias2){
  int idx = blockIdx.x*256 + threadIdx.x;
  if (idx < SZ_W2T){
    int j = idx % G4; int kk = (idx / G4) % ZK; int s = idx / (G4*ZK);
    float v = (kk < II) ? Wih[(s*G4 + j)*II + kk] : Whh[(s*G4 + j)*HH + (kk - II)];
    w2t[idx] = v;
  }
  if (idx < SZ_BIAS2) bias2[idx] = bih[idx] + bhh[idx];
}

// ubig[h][col]: col<1280 Ui[k][h][d]; <2560 Uc; <2688 Uf[h][d]; <2816 Uo; else Wa.
__global__ __launch_bounds__(256) void prep_ubig(const float* __restrict__ Ui, const float* __restrict__ Uc,
                                                 const float* __restrict__ Uf, const float* __restrict__ Uo,
                                                 const float* __restrict__ Wa, float* __restrict__ ubig){
  int idx = blockIdx.x*256 + threadIdx.x;
  if (idx >= SZ_UBIG) return;
  int col = idx % NCOL; int h = idx / NCOL;
  float v;
  if (col < 1280){ int k = col >> 7, d = col & 127; v = Ui[(k*HH + h)*HH + d]; }
  else if (col < 2560){ int c2 = col - 1280; int k = c2 >> 7, d = c2 & 127; v = Uc[(k*HH + h)*HH + d]; }
  else if (col < 2688){ v = Uf[h*HH + (col - 2560)]; }
  else if (col < 2816){ v = Uo[h*HH + (col - 2688)]; }
  else               { v = Wa[h*HH + (col - 2816)]; }
  ubig[idx] = v;
}

// ---------------- phase B: fused 10x LSTM scan (unchanged) ----------------
__global__ __launch_bounds__(512) void lstm_scan(const float* __restrict__ feat, const float* __restrict__ w2t,
                                                 const float* __restrict__ bias2, float* __restrict__ tilde){
  int p = blockIdx.x;                 // 0..159
  int g = (p & 7) * 20 + (p >> 3);
  int s = g >> 4; int rb = g & 15; int b0 = rb * 8;
  int tid = threadIdx.x;
  __shared__ float z[8][ZK];
  __shared__ float gl[8][G4];
  const float* w2ts = w2t + s*ZK*G4;
  float bj = bias2[s*G4 + tid];
  float c0 = 0.f, c1 = 0.f;
  {
    int q = tid*2; int r = q >> 7; int k = q & 127;
    z[r][128+k] = 0.f; z[r][128+k+1] = 0.f;
    const float* xrow = feat + ((s*TT + 0)*BB + (b0+r))*II;
    float2 xv = *(const float2*)(xrow + k);
    z[r][k] = xv.x; z[r][k+1] = xv.y;
  }
  __syncthreads();
  for (int t = 0; t < TT; ++t){
    float acc[8];
    #pragma unroll
    for (int r=0;r<8;++r) acc[r] = bj;
    for (int kk = 0; kk < ZK; kk += 4){
      const float* wp = w2ts + kk*G4 + tid;
      float w0 = wp[0], w1 = wp[G4], w2 = wp[2*G4], w3 = wp[3*G4];
      #pragma unroll
      for (int r=0;r<8;++r){
        float4 zv = *(const float4*)&z[r][kk];
        acc[r] = fmaf(zv.w, w3, fmaf(zv.z, w2, fmaf(zv.y, w1, fmaf(zv.x, w0, acc[r]))));
      }
    }
    int gtype = tid >> 7;
    #pragma unroll
    for (int r=0;r<8;++r){
      float v = acc[r];
      v = (gtype == 2) ? tanhf(v) : sigf(v);
      gl[r][tid] = v;
    }
    __syncthreads();
    {
      int q = tid*2; int r = q >> 7; int k = q & 127;
      float si0 = gl[r][k],     si1 = gl[r][k+1];
      float sf0 = gl[r][128+k], sf1 = gl[r][128+k+1];
      float tg0 = gl[r][256+k], tg1 = gl[r][256+k+1];
      float so0 = gl[r][384+k], so1 = gl[r][384+k+1];
      c0 = sf0*c0 + si0*tg0;
      c1 = sf1*c1 + si1*tg1;
      float h0 = so0*tanhf(c0), h1 = so1*tanhf(c1);
      z[r][128+k] = h0; z[r][128+k+1] = h1;
      float2 tv = make_float2(fmaxf(h0,0.f), fmaxf(h1,0.f));
      *(float2*)&tilde[((s*TT + t)*BB + (b0+r))*HH + k] = tv;
      if (t+1 < TT){
        const float* xrow = feat + ((s*TT + (t+1))*BB + (b0+r))*II;
        float2 xv = *(const float2*)(xrow + k);
        z[r][k] = xv.x; z[r][k+1] = xv.y;
      }
    }
    __syncthreads();
  }
}

// ---------------- phase C: projections (unchanged) ----------------
__global__ __launch_bounds__(256) void proj_ic(const float* __restrict__ tilde,
                                               const float* __restrict__ Wi, const float* __restrict__ bi,
                                               const float* __restrict__ Wc, const float* __restrict__ bc,
                                               float* __restrict__ xi, float* __restrict__ xc){
  const int k = blockIdx.y;
  const int isc = blockIdx.z;
  const float* W = (isc ? Wc : Wi) + k*HH*HH;
  const float* bias = (isc ? bc : bi) + k*HH;
  float* out = isc ? xc : xi;
  const int m0 = blockIdx.x * 128;
  const int tid = threadIdx.x;
  __shared__ float Wl[HH*HH];
  __shared__ float Al[32*HH];
  for (int u = 0; u < 64; ++u) Wl[u*256 + tid] = W[u*256 + tid];
  const int tx = tid & 31, ty = tid >> 5;
  const int d0 = tx*4;
  float4 bv = *(const float4*)&bias[d0];
  __syncthreads();
  for (int ch = 0; ch < 4; ++ch){
    const float* Arow = tilde + (size_t)(k*TT*BB + m0 + ch*32)*HH;
    #pragma unroll
    for (int u = 0; u < 4; ++u)
      *(float4*)&Al[u*1024 + tid*4] = *(const float4*)&Arow[u*1024 + tid*4];
    __syncthreads();
    float4 a0 = bv, a1 = bv, a2 = bv, a3 = bv;
    for (int h = 0; h < HH; ++h){
      float4 w4 = *(const float4*)&Wl[h*HH + d0];
      float A0 = Al[(ty   )*HH + h], A1 = Al[(ty+ 8)*HH + h];
      float A2 = Al[(ty+16)*HH + h], A3 = Al[(ty+24)*HH + h];
      a0.x = fmaf(A0,w4.x,a0.x); a0.y = fmaf(A0,w4.y,a0.y); a0.z = fmaf(A0,w4.z,a0.z); a0.w = fmaf(A0,w4.w,a0.w);
      a1.x = fmaf(A1,w4.x,a1.x); a1.y = fmaf(A1,w4.y,a1.y); a1.z = fmaf(A1,w4.z,a1.z); a1.w = fmaf(A1,w4.w,a1.w);
      a2.x = fmaf(A2,w4.x,a2.x); a2.y = fmaf(A2,w4.y,a2.y); a2.z = fmaf(A2,w4.z,a2.z); a2.w = fmaf(A2,w4.w,a2.w);
      a3.x = fmaf(A3,w4.x,a3.x); a3.y = fmaf(A3,w4.y,a3.y); a3.z = fmaf(A3,w4.z,a3.z); a3.w = fmaf(A3,w4.w,a3.w);
    }
    float4 accs[4] = {a0,a1,a2,a3};
    #pragma unroll
    for (int i = 0; i < 4; ++i){
      int m = m0 + ch*32 + ty + 8*i;
      int t = m >> 7, b = m & 127;
      *(float4*)&out[((t*SS + k)*BB + b)*HH + d0] = accs[i];
    }
    __syncthreads();
  }
}

__global__ __launch_bounds__(256) void proj_fo(const float* __restrict__ tilde,
                                               const float* __restrict__ Wf, const float* __restrict__ bf,
                                               const float* __restrict__ Wo, const float* __restrict__ bo,
                                               float* __restrict__ xf, float* __restrict__ xo){
  const int iso = blockIdx.y;
  const float* W = iso ? Wo : Wf;
  const float* bias = iso ? bo : bf;
  float* out = iso ? xo : xf;
  const int m0 = blockIdx.x * 128;
  const int tid = threadIdx.x;
  __shared__ float Wl[HH*HH];
  __shared__ float Al[32*HH];
  for (int u = 0; u < 64; ++u) Wl[u*256 + tid] = W[u*256 + tid];
  const int tx = tid & 31, ty = tid >> 5;
  const int d0 = tx*4;
  float4 bv = *(const float4*)&bias[d0];
  __syncthreads();
  for (int ch = 0; ch < 4; ++ch){
    const float* Arow = tilde + (size_t)(m0 + ch*32)*HH;
    #pragma unroll
    for (int u = 0; u < 4; ++u)
      *(float4*)&Al[u*1024 + tid*4] = *(const float4*)&Arow[u*1024 + tid*4];
    __syncthreads();
    float4 a0 = bv, a1 = bv, a2 = bv, a3 = bv;
    for (int h = 0; h < HH; ++h){
      float4 w4 = *(const float4*)&Wl[h*HH + d0];
      float A0 = Al[(ty   )*HH + h], A1 = Al[(ty+ 8)*HH + h];
      float A2 = Al[(ty+16)*HH + h], A3 = Al[(ty+24)*HH + h];
      a0.x = fmaf(A0,w4.x,a0.x); a0.y = fmaf(A0,w4.y,a0.y); a0.z = fmaf(A0,w4.z,a0.z); a0.w = fmaf(A0,w4.w,a0.w);
      a1.x = fmaf(A1,w4.x,a1.x); a1.y = fmaf(A1,w4.y,a1.y); a1.z = fmaf(A1,w4.z,a1.z); a1.w = fmaf(A1,w4.w,a1.w);
      a2.x = fmaf(A2,w4.x,a2.x); a2.y = fmaf(A2,w4.y,a2.y); a2.z = fmaf(A2,w4.z,a2.z); a2.w = fmaf(A2,w4.w,a2.w);
      a3.x = fmaf(A3,w4.x,a3.x); a3.y = fmaf(A3,w4.y,a3.y); a3.z = fmaf(A3,w4.z,a3.z); a3.w = fmaf(A3,w4.w,a3.w);
    }
    float4 accs[4] = {a0,a1,a2,a3};
    #pragma unroll
    for (int i = 0; i < 4; ++i){
      int m = m0 + ch*32 + ty + 8*i;
      *(float4*)&out[(size_t)m*HH + d0] = accs[i];
    }
    __syncthreads();
  }
}

// ---------------- phase D: cooperative weight-stationary MI-LSTM scan ----------------
__device__ __forceinline__ void gbar(int* cnt, int target){
  __syncthreads();
  if (threadIdx.x == 0){
    __hip_atomic_fetch_add(cnt, 1, __ATOMIC_RELEASE, __HIP_MEMORY_SCOPE_AGENT);
    while (__hip_atomic_load(cnt, __ATOMIC_RELAXED, __HIP_MEMORY_SCOPE_AGENT) < target)
      __builtin_amdgcn_s_sleep(1);
    (void)__hip_atomic_load(cnt, __ATOMIC_ACQUIRE, __HIP_MEMORY_SCOPE_AGENT);
  }
  __syncthreads();
}

__global__ void zero_cnt(int* cnt){ if (threadIdx.x == 0) *cnt = 0; }

// 92 blocks x 512 threads (cooperative). Block bk owns 32 Ubig columns
// (LDS-resident for the whole scan). Per step: [stage h/c 64KB -> LDS],
// GEMM 32cols x 128b, barrier, pointwise (blocks 0..63, 2 rows each), barrier.
__global__ __launch_bounds__(512) void mi_coop(
    const float* __restrict__ ubig,
    const float* __restrict__ xi, const float* __restrict__ xc,
    const float* __restrict__ xf, const float* __restrict__ xo,
    const float* __restrict__ headW, const float* __restrict__ headb,
    float* __restrict__ hT, float* __restrict__ cT,
    float* __restrict__ act, int* cnt, float* __restrict__ out)
{
  const int bk = blockIdx.x;
  const int tid = threadIdx.x;
  __shared__ float Wl[128*32];                 // 16KB weights, persistent
  __shared__ __align__(16) float avL[128*128]; // 64KB h (or c) stage
  __shared__ float lL[20*128];                 // P: l[row][k][d]
  __shared__ float part[8][8];
  __shared__ float uL[2][10];
  const int col = tid & 31, rg = tid >> 5;     // rg: 16 groups of 8 rows
  const int gcol = bk*32 + col;
  for (int h = rg; h < 128; h += 16) Wl[h*32 + col] = ubig[(size_t)h*NCOL + gcol];

  int btype; const float* xptr = nullptr; size_t xstr = 0;
  if (bk < 40){ btype = 0; int k = bk>>2;      xptr = xi + (size_t)k*BB*HH + ((bk&3)*32 + col);      xstr = (size_t)SS*BB*HH; }
  else if (bk < 80){ btype = 1; int k = (bk-40)>>2; xptr = xc + (size_t)k*BB*HH + (((bk-40)&3)*32 + col); xstr = (size_t)SS*BB*HH; }
  else if (bk < 84){ btype = 2; xptr = xf + ((bk-80)*32 + col); xstr = (size_t)BB*HH; }
  else if (bk < 88){ btype = 3; xptr = xo + ((bk-84)*32 + col); xstr = (size_t)BB*HH; }
  else { btype = 4; }

  const int prow = tid >> 8, pd = tid & 127, phalf = (tid >> 7) & 1;
  const int pb = bk*2 + prow;
  const bool isP = (bk < 64);
  float c_reg = 0.f;
  float hw = headW[pd];
  float hb = headb[0];
  if (isP && phalf == 0){ hT[pd*BB + pb] = 0.f; cT[pd*BB + pb] = 0.f; }

  int phase = 1;
  gbar(cnt, (phase++)*NBLK);

  for (int t = 0; t < TT; ++t){
    // ---------- G: act[b][gcol] = activation(xbase + state @ Ubig[:,gcol]) ----------
    const float* src = (btype == 4) ? cT : hT;
    #pragma unroll
    for (int u = 0; u < 8; ++u)
      *(float4*)&avL[(u*512 + tid)*4] = *(const float4*)&src[(u*512 + tid)*4];
    float acc[8];
    if (btype == 4){
      #pragma unroll
      for (int j = 0; j < 8; ++j) acc[j] = 0.f;
    } else {
      const float* p = xptr + (size_t)t*xstr + (size_t)(rg*8)*HH;
      #pragma unroll
      for (int j = 0; j < 8; ++j) acc[j] = p[(size_t)j*HH];
    }
    __syncthreads();
    #pragma unroll 4
    for (int h = 0; h < 128; ++h){
      float w = Wl[h*32 + col];
      float4 a0 = *(const float4*)&avL[h*128 + rg*8];
      float4 a1 = *(const float4*)&avL[h*128 + rg*8 + 4];
      acc[0] = fmaf(w, a0.x, acc[0]);
      acc[1] = fmaf(w, a0.y, acc[1]);
      acc[2] = fmaf(w, a0.z, acc[2]);
      acc[3] = fmaf(w, a0.w, acc[3]);
      acc[4] = fmaf(w, a1.x, acc[4]);
      acc[5] = fmaf(w, a1.y, acc[5]);
      acc[6] = fmaf(w, a1.z, acc[6]);
      acc[7] = fmaf(w, a1.w, acc[7]);
    }
    #pragma unroll
    for (int j = 0; j < 8; ++j){
      float v = acc[j];
      if (btype == 1) v = tanhf(v);
      else if (btype != 4) v = sigf(v);
      act[(size_t)(rg*8 + j)*NCOL + gcol] = v;
    }
    gbar(cnt, (phase++)*NBLK);
    // ---------- P: attention + cell update (blocks 0..63, 2 rows each) ----------
    const float* arow = act + (size_t)(isP ? pb : 0)*NCOL;
    if (isP){
      float cw = arow[2816 + pd];
      float s5[5];
      #pragma unroll
      for (int j = 0; j < 5; ++j){
        int k = phalf + 2*j;
        float li = arow[k*128 + pd] * arow[1280 + k*128 + pd];
        lL[(prow*10 + k)*128 + pd] = li;
        s5[j] = li * cw;
      }
      #pragma unroll
      for (int j = 0; j < 5; ++j){
        float s = s5[j];
        s += __shfl_down(s, 32); s += __shfl_down(s, 16); s += __shfl_down(s, 8);
        s += __shfl_down(s, 4);  s += __shfl_down(s, 2);  s += __shfl_down(s, 1);
        if ((tid & 63) == 0) part[tid >> 6][j] = s;
      }
    }
    __syncthreads();
    if (isP && tid < 20){
      int row = tid / 10, k = tid - row*10;
      int wbase = row*4 + (k & 1)*2;
      uL[row][k] = tanhf(part[wbase][k >> 1] + part[wbase + 1][k >> 1]);
    }
    __syncthreads();
    if (isP){
      float m = uL[prow][0];
      #pragma unroll
      for (int k = 1; k < 10; ++k) m = fmaxf(m, uL[prow][k]);
      float e[10]; float es = 0.f;
      #pragma unroll
      for (int k = 0; k < 10; ++k){ e[k] = expf(uL[prow][k] - m); es += e[k]; }
      float inv = 1.f / es;
      float sh = 0.f;
      if (phalf == 0){
        float lm = 0.f;
        #pragma unroll
        for (int k = 0; k < 10; ++k) lm = fmaf(e[k]*inv, lL[(prow*10 + k)*128 + pd], lm);
        float f = arow[2560 + pd];
        float o = arow[2688 + pd];
        float cn = fmaf(f, c_reg, lm);
        float hn = o * tanhf(cn);
        c_reg = cn;
        hT[pd*BB + pb] = hn;
        cT[pd*BB + pb] = cn;
        sh = fmaxf(hn, 0.f) * hw;
      }
      float s = sh;
      s += __shfl_down(s, 32); s += __shfl_down(s, 16); s += __shfl_down(s, 8);
      s += __shfl_down(s, 4);  s += __shfl_down(s, 2);  s += __shfl_down(s, 1);
      if ((tid & 63) == 0) part[tid >> 6][6] = s;
    }
    __syncthreads();
    if (isP && tid < 2){
      float s = part[tid*4][6] + part[tid*4 + 1][6];
      out[t*BB + bk*2 + tid] = fmaxf(s + hb, 0.f);
    }
    gbar(cnt, (phase++)*NBLK);
  }
}

extern "C" void kernel_launch(void* const* d_in, const int* in_sizes, int n_in,
                              void* d_out, int out_size, void* d_ws, size_t ws_size,
                              hipStream_t stream) {
  const float* feat  = (const float*)d_in[0];
  const float* Wih   = (const float*)d_in[1];
  const float* Whh   = (const float*)d_in[2];
  const float* bih   = (const float*)d_in[3];
  const float* bhh   = (const float*)d_in[4];
  const float* miWi  = (const float*)d_in[5];
  const float* miUi  = (const float*)d_in[6];
  const float* mibi  = (const float*)d_in[7];
  const float* miWc  = (const float*)d_in[8];
  const float* miUc  = (const float*)d_in[9];
  const float* mibc  = (const float*)d_in[10];
  const float* miWf  = (const float*)d_in[11];
  const float* miUf  = (const float*)d_in[12];
  const float* mibf  = (const float*)d_in[13];
  const float* miWo  = (const float*)d_in[14];
  const float* miUo  = (const float*)d_in[15];
  const float* mibo  = (const float*)d_in[16];
  const float* miWa  = (const float*)d_in[17];
  const float* headW = (const float*)d_in[18];
  const float* headb = (const float*)d_in[19];
  float* out = (float*)d_out;

  float* ws    = (float*)d_ws;
  float* w2t   = ws + OFF_W2T;
  float* bias2 = ws + OFF_BIAS2;
  float* ubig  = ws + OFF_UBIG;
  float* tilde = ws + OFF_TILDE;
  float* xi    = ws + OFF_XI;
  float* xc    = ws + OFF_XC;
  float* xf    = ws + OFF_XF;
  float* xo    = ws + OFF_XO;
  float* hT    = ws + OFF_HT;
  float* cT    = ws + OFF_CT;
  float* act   = ws + OFF_ACT;
  int*   cnt   = (int*)(ws + OFF_CNT);

  prep_w2t<<<dim3(SZ_W2T/256), dim3(256), 0, stream>>>(Wih, Whh, bih, bhh, w2t, bias2);
  prep_ubig<<<dim3((SZ_UBIG+255)/256), dim3(256), 0, stream>>>(miUi, miUc, miUf, miUo, miWa, ubig);
  zero_cnt<<<dim3(1), dim3(64), 0, stream>>>(cnt);
  lstm_scan<<<dim3(160), dim3(512), 0, stream>>>(feat, w2t, bias2, tilde);
  proj_ic<<<dim3(256, SS, 2), dim3(256), 0, stream>>>(tilde, miWi, mibi, miWc, mibc, xi, xc);
  proj_fo<<<dim3(256, 2), dim3(256), 0, stream>>>(tilde, miWf, mibf, miWo, mibo, xf, xo);

  void* kargs[] = { (void*)&ubig, (void*)&xi, (void*)&xc, (void*)&xf, (void*)&xo,
                    (void*)&headW, (void*)&headb, (void*)&hT, (void*)&cT,
                    (void*)&act, (void*)&cnt, (void*)&out };
  hipLaunchCooperativeKernel((const void*)mi_coop, dim3(NBLK), dim3(512), kargs, 0, stream);
}